// Round 1
// baseline (1092.166 us; speedup 1.0000x reference)
//
#include <hip/hip_runtime.h>
#include <math.h>

#define N4C 32768
#define N3C 65536
#define N2C 131072
#define N1C 262144

typedef __bf16 bf16x8 __attribute__((ext_vector_type(8)));
typedef float f32x4 __attribute__((ext_vector_type(4)));

__device__ __forceinline__ f32x4 mfma16(bf16x8 a, bf16x8 b, f32x4 c) {
  return __builtin_amdgcn_mfma_f32_16x16x32_bf16(a, b, c, 0, 0, 0);
}

__device__ __forceinline__ float celuf(float x) { return x > 0.f ? x : expm1f(x); }

__device__ __forceinline__ float logsigf(float x) {
  // log_sigmoid(x) = -softplus(-x), numerically stable both sides
  return x < 0.f ? (x - log1pf(expf(x))) : (-log1pf(expf(-x)));
}

// split f32 -> bf16 hi + bf16 lo (error feedback); hi+lo carries ~16 mantissa bits
__device__ __forceinline__ void split8(const float* v, bf16x8& hi, bf16x8& lo) {
#pragma unroll
  for (int j = 0; j < 8; ++j) {
    float f = v[j];
    __bf16 h = (__bf16)f;
    hi[j] = h;
    lo[j] = (__bf16)(f - (float)h);
  }
}

// ---------------------------------------------------------------------------
// Level 3: PointConv (c_in=64 -> c_mid=64 -> c_out=32), MFMA bf16 hi/lo split.
// One wave per output point: 16 edges = M-tile. K=67 padded to 3 chunks of 32.
// A frags gathered straight from global; B frags (weights) live in VGPRs for
// the whole point loop. Layer-a -> layer-b via per-wave LDS round trip
// (stride 76 floats: 16B aligned for b128 reads, <=2-way bank conflicts).
// ---------------------------------------------------------------------------
__global__ __launch_bounds__(256) void l3_kernel(
    const float* __restrict__ z_mask, const float* __restrict__ pos4,
    const float* __restrict__ pos3, const int* __restrict__ src3,
    const float* __restrict__ w1a, const float* __restrict__ b1a,
    const float* __restrict__ w1b, const float* __restrict__ b1b,
    float* __restrict__ x3) {
  __shared__ float hbuf[4][16 * 76];
  const int lane = threadIdx.x & 63;
  const int wid = threadIdx.x >> 6;
  const int col = lane & 15;   // MFMA n / C col / A row m
  const int quad = lane >> 4;  // MFMA k-subchunk selector
  float* hw = hbuf[wid];

  // B fragments for layer a: B[k][n], k = c*32 + quad*8 + j, n = t*16 + col
  bf16x8 BaH[3][4], BaL[3][4];
#pragma unroll
  for (int c = 0; c < 3; ++c)
#pragma unroll
    for (int t = 0; t < 4; ++t) {
      float v[8];
#pragma unroll
      for (int j = 0; j < 8; ++j) {
        int k = c * 32 + quad * 8 + j;
        v[j] = (k < 67) ? w1a[k * 64 + t * 16 + col] : 0.f;
      }
      split8(v, BaH[c][t], BaL[c][t]);
    }
  // B fragments for layer b: W1b [64][32]
  bf16x8 BbH[2][2], BbL[2][2];
#pragma unroll
  for (int c = 0; c < 2; ++c)
#pragma unroll
    for (int t = 0; t < 2; ++t) {
      float v[8];
#pragma unroll
      for (int j = 0; j < 8; ++j) {
        int k = c * 32 + quad * 8 + j;
        v[j] = w1b[k * 32 + t * 16 + col];
      }
      split8(v, BbH[c][t], BbL[c][t]);
    }
  const float biasA0 = b1a[col], biasA1 = b1a[16 + col];
  const float biasA2 = b1a[32 + col], biasA3 = b1a[48 + col];
  const float biasB0 = b1b[col], biasB1 = b1b[16 + col];

  const int gwave = blockIdx.x * 4 + wid;
  const int nw = gridDim.x * 4;
  for (int p = gwave; p < N3C; p += nw) {
    const int s = src3[p * 16 + col];  // edge m = col; all quads same src
    const float po0 = pos3[p * 3 + 0], po1 = pos3[p * 3 + 1], po2 = pos3[p * 3 + 2];

    // ---- A fragments: feat[k] = [z_mask[s][0..63], rel[0..2], 0-pad] ----
    const float* zr = z_mask + (size_t)s * 64;
    float a0[8], a1[8], a2[8];
    {
      float4 f0 = *(const float4*)(zr + quad * 8);
      float4 f1 = *(const float4*)(zr + quad * 8 + 4);
      float4 f2 = *(const float4*)(zr + 32 + quad * 8);
      float4 f3 = *(const float4*)(zr + 32 + quad * 8 + 4);
      a0[0] = f0.x; a0[1] = f0.y; a0[2] = f0.z; a0[3] = f0.w;
      a0[4] = f1.x; a0[5] = f1.y; a0[6] = f1.z; a0[7] = f1.w;
      a1[0] = f2.x; a1[1] = f2.y; a1[2] = f2.z; a1[3] = f2.w;
      a1[4] = f3.x; a1[5] = f3.y; a1[6] = f3.z; a1[7] = f3.w;
    }
#pragma unroll
    for (int j = 0; j < 8; ++j) a2[j] = 0.f;
    if (quad == 0) {
      a2[0] = pos4[s * 3 + 0] - po0;
      a2[1] = pos4[s * 3 + 1] - po1;
      a2[2] = pos4[s * 3 + 2] - po2;
    }
    bf16x8 AH[3], AL[3];
    split8(a0, AH[0], AL[0]);
    split8(a1, AH[1], AL[1]);
    split8(a2, AH[2], AL[2]);

    // ---- layer a: h = celu(feat @ W1a + b1a), D tiles n = t*16+col ----
    f32x4 d[4];
#pragma unroll
    for (int t = 0; t < 4; ++t) {
      f32x4 acc = {0.f, 0.f, 0.f, 0.f};
#pragma unroll
      for (int c = 0; c < 3; ++c) {
        acc = mfma16(AH[c], BaH[c][t], acc);
        acc = mfma16(AH[c], BaL[c][t], acc);
        acc = mfma16(AL[c], BaH[c][t], acc);
      }
      d[t] = acc;
    }
    // C layout: row = quad*4 + r, col = n. Store celu(h) to LDS [16][76].
#pragma unroll
    for (int r = 0; r < 4; ++r) {
      float* bp = hw + (quad * 4 + r) * 76 + col;
      bp[0]  = celuf(d[0][r] + biasA0);
      bp[16] = celuf(d[1][r] + biasA1);
      bp[32] = celuf(d[2][r] + biasA2);
      bp[48] = celuf(d[3][r] + biasA3);
    }
    // Same-wave LDS ops execute in order; no cross-wave sharing -> no barrier.
    // ---- layer b: m = h @ W1b + b1b; A'[m=col][k = c*32 + quad*8 + j] ----
    bf16x8 PH[2], PL[2];
#pragma unroll
    for (int c = 0; c < 2; ++c) {
      const float* rp = hw + col * 76 + c * 32 + quad * 8;
      float v[8];
      float4 g0 = *(const float4*)rp;
      float4 g1 = *(const float4*)(rp + 4);
      v[0] = g0.x; v[1] = g0.y; v[2] = g0.z; v[3] = g0.w;
      v[4] = g1.x; v[5] = g1.y; v[6] = g1.z; v[7] = g1.w;
      split8(v, PH[c], PL[c]);
    }
    f32x4 e[2];
#pragma unroll
    for (int t = 0; t < 2; ++t) {
      f32x4 acc = {0.f, 0.f, 0.f, 0.f};
#pragma unroll
      for (int c = 0; c < 2; ++c) {
        acc = mfma16(PH[c], BbH[c][t], acc);
        acc = mfma16(PH[c], BbL[c][t], acc);
        acc = mfma16(PL[c], BbH[c][t], acc);
      }
      e[t] = acc;
    }
    // segment_max over the 16 edge rows: 4 regs (rows quad*4+r) then quads.
    float m0 = fmaxf(fmaxf(e[0][0], e[0][1]), fmaxf(e[0][2], e[0][3]));
    float m1 = fmaxf(fmaxf(e[1][0], e[1][1]), fmaxf(e[1][2], e[1][3]));
    m0 = fmaxf(m0, __shfl_xor(m0, 16, 64));
    m0 = fmaxf(m0, __shfl_xor(m0, 32, 64));
    m1 = fmaxf(m1, __shfl_xor(m1, 16, 64));
    m1 = fmaxf(m1, __shfl_xor(m1, 32, 64));
    if (lane < 16) {
      x3[(size_t)p * 32 + col]      = celuf(m0 + biasB0);  // bias after max: max(x)+b == max(x+b)
      x3[(size_t)p * 32 + 16 + col] = celuf(m1 + biasB1);
    }
  }
}

// ---------------------------------------------------------------------------
// Level 2: PointConv (32 -> 16 -> 16), scalar fp32, one thread per out point.
// Weights read with uniform constant indices -> s_load (scalar cache), so the
// VALU fmacs are the bottleneck, not an LDS broadcast.
// ---------------------------------------------------------------------------
__global__ __launch_bounds__(256) void l2_kernel(
    const float* __restrict__ x3, const float* __restrict__ pos3,
    const float* __restrict__ pos2, const int* __restrict__ src2,
    const float* __restrict__ w2a, const float* __restrict__ b2a,
    const float* __restrict__ w2b, const float* __restrict__ b2b,
    float* __restrict__ x2) {
  const int q = blockIdx.x * 256 + threadIdx.x;
  if (q >= N2C) return;
  const float po0 = pos2[q * 3 + 0], po1 = pos2[q * 3 + 1], po2 = pos2[q * 3 + 2];
  float acc[16];
#pragma unroll
  for (int c = 0; c < 16; ++c) acc[c] = -INFINITY;
  for (int j = 0; j < 16; ++j) {
    const int s = src2[q * 16 + j];
    float feat[32];
    const float4* xr = (const float4*)(x3 + (size_t)s * 32);
#pragma unroll
    for (int v = 0; v < 8; ++v) {
      float4 t = xr[v];
      feat[v * 4 + 0] = t.x; feat[v * 4 + 1] = t.y;
      feat[v * 4 + 2] = t.z; feat[v * 4 + 3] = t.w;
    }
    const float r0 = pos3[s * 3 + 0] - po0;
    const float r1 = pos3[s * 3 + 1] - po1;
    const float r2 = pos3[s * 3 + 2] - po2;
    float m[16];
#pragma unroll
    for (int c = 0; c < 16; ++c) m[c] = b2b[c];
#pragma unroll
    for (int l = 0; l < 16; ++l) {
      float h = b2a[l];
#pragma unroll
      for (int k = 0; k < 32; ++k) h = fmaf(feat[k], w2a[k * 16 + l], h);
      h = fmaf(r0, w2a[512 + l], h);
      h = fmaf(r1, w2a[528 + l], h);
      h = fmaf(r2, w2a[544 + l], h);
      h = celuf(h);
#pragma unroll
      for (int c = 0; c < 16; ++c) m[c] = fmaf(h, w2b[l * 16 + c], m[c]);
    }
#pragma unroll
    for (int c = 0; c < 16; ++c) acc[c] = fmaxf(acc[c], m[c]);
  }
  float4* xo = (float4*)(x2 + (size_t)q * 16);
#pragma unroll
  for (int v = 0; v < 4; ++v) {
    float4 t;
    t.x = celuf(acc[v * 4 + 0]); t.y = celuf(acc[v * 4 + 1]);
    t.z = celuf(acc[v * 4 + 2]); t.w = celuf(acc[v * 4 + 3]);
    xo[v] = t;
  }
}

// ---------------------------------------------------------------------------
// Level 1: PointConv (16 -> 8 -> 8) + fused final linear + log_sigmoid.
// ---------------------------------------------------------------------------
__global__ __launch_bounds__(256) void l1_kernel(
    const float* __restrict__ x2, const float* __restrict__ pos2,
    const float* __restrict__ pos1, const int* __restrict__ src1,
    const float* __restrict__ w3a, const float* __restrict__ b3a,
    const float* __restrict__ w3b, const float* __restrict__ b3b,
    const float* __restrict__ wlin, const float* __restrict__ blin,
    float* __restrict__ out) {
  const int q = blockIdx.x * 256 + threadIdx.x;
  if (q >= N1C) return;
  const float po0 = pos1[q * 3 + 0], po1 = pos1[q * 3 + 1], po2 = pos1[q * 3 + 2];
  float acc[8];
#pragma unroll
  for (int c = 0; c < 8; ++c) acc[c] = -INFINITY;
  for (int j = 0; j < 16; ++j) {
    const int s = src1[q * 16 + j];
    float feat[16];
    const float4* xr = (const float4*)(x2 + (size_t)s * 16);
#pragma unroll
    for (int v = 0; v < 4; ++v) {
      float4 t = xr[v];
      feat[v * 4 + 0] = t.x; feat[v * 4 + 1] = t.y;
      feat[v * 4 + 2] = t.z; feat[v * 4 + 3] = t.w;
    }
    const float r0 = pos2[s * 3 + 0] - po0;
    const float r1 = pos2[s * 3 + 1] - po1;
    const float r2 = pos2[s * 3 + 2] - po2;
    float m[8];
#pragma unroll
    for (int c = 0; c < 8; ++c) m[c] = b3b[c];
#pragma unroll
    for (int l = 0; l < 8; ++l) {
      float h = b3a[l];
#pragma unroll
      for (int k = 0; k < 16; ++k) h = fmaf(feat[k], w3a[k * 8 + l], h);
      h = fmaf(r0, w3a[128 + l], h);
      h = fmaf(r1, w3a[136 + l], h);
      h = fmaf(r2, w3a[144 + l], h);
      h = celuf(h);
#pragma unroll
      for (int c = 0; c < 8; ++c) m[c] = fmaf(h, w3b[l * 8 + c], m[c]);
    }
#pragma unroll
    for (int c = 0; c < 8; ++c) acc[c] = fmaxf(acc[c], m[c]);
  }
  float logit = blin[0];
#pragma unroll
  for (int c = 0; c < 8; ++c) logit = fmaf(celuf(acc[c]), wlin[c], logit);
  out[q] = logsigf(logit);
}

extern "C" void kernel_launch(void* const* d_in, const int* in_sizes, int n_in,
                              void* d_out, int out_size, void* d_ws, size_t ws_size,
                              hipStream_t stream) {
  // setup_inputs dict order:
  // 0 z_mask, 1 pos4, 2 pos3, 3 pos2, 4 pos1, 5 g4, 6 g3, 7 g2, 8 g1,
  // 9 w1a, 10 b1a, 11 w1b, 12 b1b, 13 w2a, 14 b2a, 15 w2b, 16 b2b,
  // 17 w3a, 18 b3a, 19 w3b, 20 b3b, 21 wlin, 22 blin,
  // 23 src3, 24 dst3, 25 src2, 26 dst2, 27 src1, 28 dst1
  const float* z_mask = (const float*)d_in[0];
  const float* pos4 = (const float*)d_in[1];
  const float* pos3 = (const float*)d_in[2];
  const float* pos2 = (const float*)d_in[3];
  const float* pos1 = (const float*)d_in[4];
  const float* w1a = (const float*)d_in[9];
  const float* b1a = (const float*)d_in[10];
  const float* w1b = (const float*)d_in[11];
  const float* b1b = (const float*)d_in[12];
  const float* w2a = (const float*)d_in[13];
  const float* b2a = (const float*)d_in[14];
  const float* w2b = (const float*)d_in[15];
  const float* b2b = (const float*)d_in[16];
  const float* w3a = (const float*)d_in[17];
  const float* b3a = (const float*)d_in[18];
  const float* w3b = (const float*)d_in[19];
  const float* b3b = (const float*)d_in[20];
  const float* wlin = (const float*)d_in[21];
  const float* blin = (const float*)d_in[22];
  const int* src3 = (const int*)d_in[23];
  const int* src2 = (const int*)d_in[25];
  const int* src1 = (const int*)d_in[27];

  float* x3 = (float*)d_ws;                 // [N3][32] = 8 MB
  float* x2 = x3 + (size_t)N3C * 32;        // [N2][16] = 8 MB (ws >= 16 MB)
  float* out = (float*)d_out;               // [N1] log-sigmoid logits

  l3_kernel<<<1024, 256, 0, stream>>>(z_mask, pos4, pos3, src3, w1a, b1a, w1b, b1b, x3);
  l2_kernel<<<N2C / 256, 256, 0, stream>>>(x3, pos3, pos2, src2, w2a, b2a, w2b, b2b, x2);
  l1_kernel<<<N1C / 256, 256, 0, stream>>>(x2, pos2, pos1, src1, w3a, b3a, w3b, b3b,
                                           wlin, blin, out);
}

// Round 2
// 436.605 us; speedup vs baseline: 2.5015x; 2.5015x over previous
//
#include <hip/hip_runtime.h>
#include <math.h>

#define N4C 32768
#define N3C 65536
#define N2C 131072
#define N1C 262144

typedef __bf16 bf16x8 __attribute__((ext_vector_type(8)));
typedef float f32x4 __attribute__((ext_vector_type(4)));

__device__ __forceinline__ f32x4 mfma16(bf16x8 a, bf16x8 b, f32x4 c) {
  return __builtin_amdgcn_mfma_f32_16x16x32_bf16(a, b, c, 0, 0, 0);
}

__device__ __forceinline__ float celuf(float x) { return x > 0.f ? x : expm1f(x); }

__device__ __forceinline__ float logsigf(float x) {
  // log_sigmoid(x) = -softplus(-x), numerically stable both sides
  return x < 0.f ? (x - log1pf(expf(x))) : (-log1pf(expf(-x)));
}

// split f32 -> bf16 hi + bf16 lo (error feedback); hi+lo carries ~16 mantissa bits
__device__ __forceinline__ void split8(const float* v, bf16x8& hi, bf16x8& lo) {
#pragma unroll
  for (int j = 0; j < 8; ++j) {
    float f = v[j];
    __bf16 h = (__bf16)f;
    hi[j] = h;
    lo[j] = (__bf16)(f - (float)h);
  }
}

// ---------------------------------------------------------------------------
// Level 3: PointConv (c_in=64 -> c_mid=64 -> c_out=32), MFMA bf16 hi/lo split.
// One wave per output point: 16 edges = M-tile. K=67 padded to 3 chunks of 32.
// (unchanged from round 1 — verified correct)
// ---------------------------------------------------------------------------
__global__ __launch_bounds__(256) void l3_kernel(
    const float* __restrict__ z_mask, const float* __restrict__ pos4,
    const float* __restrict__ pos3, const int* __restrict__ src3,
    const float* __restrict__ w1a, const float* __restrict__ b1a,
    const float* __restrict__ w1b, const float* __restrict__ b1b,
    float* __restrict__ x3) {
  __shared__ float hbuf[4][16 * 76];
  const int lane = threadIdx.x & 63;
  const int wid = threadIdx.x >> 6;
  const int col = lane & 15;   // MFMA n / C col / A row m
  const int quad = lane >> 4;  // MFMA k-subchunk selector
  float* hw = hbuf[wid];

  // B fragments for layer a: B[k][n], k = c*32 + quad*8 + j, n = t*16 + col
  bf16x8 BaH[3][4], BaL[3][4];
#pragma unroll
  for (int c = 0; c < 3; ++c)
#pragma unroll
    for (int t = 0; t < 4; ++t) {
      float v[8];
#pragma unroll
      for (int j = 0; j < 8; ++j) {
        int k = c * 32 + quad * 8 + j;
        v[j] = (k < 67) ? w1a[k * 64 + t * 16 + col] : 0.f;
      }
      split8(v, BaH[c][t], BaL[c][t]);
    }
  // B fragments for layer b: W1b [64][32]
  bf16x8 BbH[2][2], BbL[2][2];
#pragma unroll
  for (int c = 0; c < 2; ++c)
#pragma unroll
    for (int t = 0; t < 2; ++t) {
      float v[8];
#pragma unroll
      for (int j = 0; j < 8; ++j) {
        int k = c * 32 + quad * 8 + j;
        v[j] = w1b[k * 32 + t * 16 + col];
      }
      split8(v, BbH[c][t], BbL[c][t]);
    }
  const float biasA0 = b1a[col], biasA1 = b1a[16 + col];
  const float biasA2 = b1a[32 + col], biasA3 = b1a[48 + col];
  const float biasB0 = b1b[col], biasB1 = b1b[16 + col];

  const int gwave = blockIdx.x * 4 + wid;
  const int nw = gridDim.x * 4;
  for (int p = gwave; p < N3C; p += nw) {
    const int s = src3[p * 16 + col];  // edge m = col; all quads same src
    const float po0 = pos3[p * 3 + 0], po1 = pos3[p * 3 + 1], po2 = pos3[p * 3 + 2];

    // ---- A fragments: feat[k] = [z_mask[s][0..63], rel[0..2], 0-pad] ----
    const float* zr = z_mask + (size_t)s * 64;
    float a0[8], a1[8], a2[8];
    {
      float4 f0 = *(const float4*)(zr + quad * 8);
      float4 f1 = *(const float4*)(zr + quad * 8 + 4);
      float4 f2 = *(const float4*)(zr + 32 + quad * 8);
      float4 f3 = *(const float4*)(zr + 32 + quad * 8 + 4);
      a0[0] = f0.x; a0[1] = f0.y; a0[2] = f0.z; a0[3] = f0.w;
      a0[4] = f1.x; a0[5] = f1.y; a0[6] = f1.z; a0[7] = f1.w;
      a1[0] = f2.x; a1[1] = f2.y; a1[2] = f2.z; a1[3] = f2.w;
      a1[4] = f3.x; a1[5] = f3.y; a1[6] = f3.z; a1[7] = f3.w;
    }
#pragma unroll
    for (int j = 0; j < 8; ++j) a2[j] = 0.f;
    if (quad == 0) {
      a2[0] = pos4[s * 3 + 0] - po0;
      a2[1] = pos4[s * 3 + 1] - po1;
      a2[2] = pos4[s * 3 + 2] - po2;
    }
    bf16x8 AH[3], AL[3];
    split8(a0, AH[0], AL[0]);
    split8(a1, AH[1], AL[1]);
    split8(a2, AH[2], AL[2]);

    // ---- layer a: h = celu(feat @ W1a + b1a), D tiles n = t*16+col ----
    f32x4 d[4];
#pragma unroll
    for (int t = 0; t < 4; ++t) {
      f32x4 acc = {0.f, 0.f, 0.f, 0.f};
#pragma unroll
      for (int c = 0; c < 3; ++c) {
        acc = mfma16(AH[c], BaH[c][t], acc);
        acc = mfma16(AH[c], BaL[c][t], acc);
        acc = mfma16(AL[c], BaH[c][t], acc);
      }
      d[t] = acc;
    }
    // C layout: row = quad*4 + r, col = n. Store celu(h) to LDS [16][76].
#pragma unroll
    for (int r = 0; r < 4; ++r) {
      float* bp = hw + (quad * 4 + r) * 76 + col;
      bp[0]  = celuf(d[0][r] + biasA0);
      bp[16] = celuf(d[1][r] + biasA1);
      bp[32] = celuf(d[2][r] + biasA2);
      bp[48] = celuf(d[3][r] + biasA3);
    }
    // Same-wave LDS ops execute in order; no cross-wave sharing -> no barrier.
    // ---- layer b: m = h @ W1b + b1b; A'[m=col][k = c*32 + quad*8 + j] ----
    bf16x8 PH[2], PL[2];
#pragma unroll
    for (int c = 0; c < 2; ++c) {
      const float* rp = hw + col * 76 + c * 32 + quad * 8;
      float v[8];
      float4 g0 = *(const float4*)rp;
      float4 g1 = *(const float4*)(rp + 4);
      v[0] = g0.x; v[1] = g0.y; v[2] = g0.z; v[3] = g0.w;
      v[4] = g1.x; v[5] = g1.y; v[6] = g1.z; v[7] = g1.w;
      split8(v, PH[c], PL[c]);
    }
    f32x4 e[2];
#pragma unroll
    for (int t = 0; t < 2; ++t) {
      f32x4 acc = {0.f, 0.f, 0.f, 0.f};
#pragma unroll
      for (int c = 0; c < 2; ++c) {
        acc = mfma16(PH[c], BbH[c][t], acc);
        acc = mfma16(PH[c], BbL[c][t], acc);
        acc = mfma16(PL[c], BbH[c][t], acc);
      }
      e[t] = acc;
    }
    // segment_max over the 16 edge rows: 4 regs (rows quad*4+r) then quads.
    float m0 = fmaxf(fmaxf(e[0][0], e[0][1]), fmaxf(e[0][2], e[0][3]));
    float m1 = fmaxf(fmaxf(e[1][0], e[1][1]), fmaxf(e[1][2], e[1][3]));
    m0 = fmaxf(m0, __shfl_xor(m0, 16, 64));
    m0 = fmaxf(m0, __shfl_xor(m0, 32, 64));
    m1 = fmaxf(m1, __shfl_xor(m1, 16, 64));
    m1 = fmaxf(m1, __shfl_xor(m1, 32, 64));
    if (lane < 16) {
      x3[(size_t)p * 32 + col]      = celuf(m0 + biasB0);  // bias after max: max(x)+b == max(x+b)
      x3[(size_t)p * 32 + 16 + col] = celuf(m1 + biasB1);
    }
  }
}

// ---------------------------------------------------------------------------
// Level 2: PointConv (32 -> 16 -> 16), MFMA wave-per-point (l3 structure).
// K_a = 35 -> 2 chunks of 32 (chunk1: rel in k=32..34). c_mid=16 -> 1 n-tile.
// Layer b: K=16 (quads 0,1 carry data), c_out=16 -> 1 n-tile.
// ---------------------------------------------------------------------------
__global__ __launch_bounds__(256) void l2_kernel(
    const float* __restrict__ x3, const float* __restrict__ pos3,
    const float* __restrict__ pos2, const int* __restrict__ src2,
    const float* __restrict__ w2a, const float* __restrict__ b2a,
    const float* __restrict__ w2b, const float* __restrict__ b2b,
    float* __restrict__ x2) {
  __shared__ float hbuf[4][16 * 20];  // stride 20 floats: 80 B rows, 16B-aligned
  const int lane = threadIdx.x & 63;
  const int wid = threadIdx.x >> 6;
  const int col = lane & 15;
  const int quad = lane >> 4;
  float* hw = hbuf[wid];

  bf16x8 BaH[2], BaL[2];
#pragma unroll
  for (int c = 0; c < 2; ++c) {
    float v[8];
#pragma unroll
    for (int j = 0; j < 8; ++j) {
      int k = c * 32 + quad * 8 + j;
      v[j] = (k < 35) ? w2a[k * 16 + col] : 0.f;
    }
    split8(v, BaH[c], BaL[c]);
  }
  bf16x8 BbH, BbL;
  {
    float v[8];
#pragma unroll
    for (int j = 0; j < 8; ++j) {
      int k = quad * 8 + j;
      v[j] = (k < 16) ? w2b[k * 16 + col] : 0.f;
    }
    split8(v, BbH, BbL);
  }
  const float biasA = b2a[col];
  const float biasB = b2b[col];

  const int gwave = blockIdx.x * 4 + wid;
  const int nw = gridDim.x * 4;
  for (int p = gwave; p < N2C; p += nw) {
    const int s = src2[p * 16 + col];
    const float po0 = pos2[p * 3 + 0], po1 = pos2[p * 3 + 1], po2 = pos2[p * 3 + 2];

    float a0[8], a1[8];
    {
      const float* xr = x3 + (size_t)s * 32 + quad * 8;
      float4 f0 = *(const float4*)xr;
      float4 f1 = *(const float4*)(xr + 4);
      a0[0] = f0.x; a0[1] = f0.y; a0[2] = f0.z; a0[3] = f0.w;
      a0[4] = f1.x; a0[5] = f1.y; a0[6] = f1.z; a0[7] = f1.w;
    }
#pragma unroll
    for (int j = 0; j < 8; ++j) a1[j] = 0.f;
    if (quad == 0) {
      a1[0] = pos3[s * 3 + 0] - po0;
      a1[1] = pos3[s * 3 + 1] - po1;
      a1[2] = pos3[s * 3 + 2] - po2;
    }
    bf16x8 AH[2], AL[2];
    split8(a0, AH[0], AL[0]);
    split8(a1, AH[1], AL[1]);

    f32x4 d = {0.f, 0.f, 0.f, 0.f};
#pragma unroll
    for (int c = 0; c < 2; ++c) {
      d = mfma16(AH[c], BaH[c], d);
      d = mfma16(AH[c], BaL[c], d);
      d = mfma16(AL[c], BaH[c], d);
    }
    // h: row = quad*4 + r (edge), col = mid channel. celu + bias -> LDS.
#pragma unroll
    for (int r = 0; r < 4; ++r)
      hw[(quad * 4 + r) * 20 + col] = celuf(d[r] + biasA);

    // layer b A-frag: A'[m=edge=col][k=mid=quad*8+j]; valid k<16 (quads 0,1)
    float v[8];
#pragma unroll
    for (int j = 0; j < 8; ++j) v[j] = 0.f;
    if (quad < 2) {
      const float* rp = hw + col * 20 + quad * 8;
      float4 g0 = *(const float4*)rp;
      float4 g1 = *(const float4*)(rp + 4);
      v[0] = g0.x; v[1] = g0.y; v[2] = g0.z; v[3] = g0.w;
      v[4] = g1.x; v[5] = g1.y; v[6] = g1.z; v[7] = g1.w;
    }
    bf16x8 PH, PL;
    split8(v, PH, PL);

    f32x4 e = {0.f, 0.f, 0.f, 0.f};
    e = mfma16(PH, BbH, e);
    e = mfma16(PH, BbL, e);
    e = mfma16(PL, BbH, e);

    float m0 = fmaxf(fmaxf(e[0], e[1]), fmaxf(e[2], e[3]));
    m0 = fmaxf(m0, __shfl_xor(m0, 16, 64));
    m0 = fmaxf(m0, __shfl_xor(m0, 32, 64));
    if (lane < 16) x2[(size_t)p * 16 + col] = celuf(m0 + biasB);
  }
}

// ---------------------------------------------------------------------------
// Level 1: PointConv (16 -> 8 -> 8) + fused final linear + log_sigmoid.
// MFMA wave-per-point. K_a = 19 -> 1 chunk (k 0..15 feat, 16..18 rel).
// c_mid=8, c_out=8: n-tile cols 0..7 valid, 8..15 zero-padded in B.
// ---------------------------------------------------------------------------
__global__ __launch_bounds__(256) void l1_kernel(
    const float* __restrict__ x2, const float* __restrict__ pos2,
    const float* __restrict__ pos1, const int* __restrict__ src1,
    const float* __restrict__ w3a, const float* __restrict__ b3a,
    const float* __restrict__ w3b, const float* __restrict__ b3b,
    const float* __restrict__ wlin, const float* __restrict__ blin,
    float* __restrict__ out) {
  __shared__ float hbuf[4][16 * 12];  // stride 12 floats: 48 B rows, 16B-aligned
  const int lane = threadIdx.x & 63;
  const int wid = threadIdx.x >> 6;
  const int col = lane & 15;
  const int quad = lane >> 4;
  float* hw = hbuf[wid];

  bf16x8 BaH, BaL;
  {
    float v[8];
#pragma unroll
    for (int j = 0; j < 8; ++j) {
      int k = quad * 8 + j;
      v[j] = (k < 19 && col < 8) ? w3a[k * 8 + col] : 0.f;
    }
    split8(v, BaH, BaL);
  }
  bf16x8 BbH, BbL;
  {
    float v[8];
#pragma unroll
    for (int j = 0; j < 8; ++j) {
      int k = quad * 8 + j;
      v[j] = (k < 8 && col < 8) ? w3b[k * 8 + col] : 0.f;
    }
    split8(v, BbH, BbL);
  }
  const float biasA = (col < 8) ? b3a[col] : 0.f;
  const float biasB = (col < 8) ? b3b[col] : 0.f;
  const float wl = (col < 8) ? wlin[col] : 0.f;
  const float bl = blin[0];

  const int gwave = blockIdx.x * 4 + wid;
  const int nw = gridDim.x * 4;
  for (int p = gwave; p < N1C; p += nw) {
    const int s = src1[p * 16 + col];
    const float po0 = pos1[p * 3 + 0], po1 = pos1[p * 3 + 1], po2 = pos1[p * 3 + 2];

    // A[m=col=edge][k=quad*8+j]: quads 0,1 = feat 0..15; quad 2 j<3 = rel; else 0
    float a0[8];
#pragma unroll
    for (int j = 0; j < 8; ++j) a0[j] = 0.f;
    if (quad < 2) {
      const float* xr = x2 + (size_t)s * 16 + quad * 8;
      float4 f0 = *(const float4*)xr;
      float4 f1 = *(const float4*)(xr + 4);
      a0[0] = f0.x; a0[1] = f0.y; a0[2] = f0.z; a0[3] = f0.w;
      a0[4] = f1.x; a0[5] = f1.y; a0[6] = f1.z; a0[7] = f1.w;
    } else if (quad == 2) {
      a0[0] = pos2[s * 3 + 0] - po0;
      a0[1] = pos2[s * 3 + 1] - po1;
      a0[2] = pos2[s * 3 + 2] - po2;
    }
    bf16x8 AH, AL;
    split8(a0, AH, AL);

    f32x4 d = {0.f, 0.f, 0.f, 0.f};
    d = mfma16(AH, BaH, d);
    d = mfma16(AH, BaL, d);
    d = mfma16(AL, BaH, d);

    // h: row = quad*4+r (edge), cols 0..7 valid -> LDS (mask col<8)
    if (col < 8) {
#pragma unroll
      for (int r = 0; r < 4; ++r)
        hw[(quad * 4 + r) * 12 + col] = celuf(d[r] + biasA);
    }
    // layer b A-frag: A'[m=edge=col][k=mid=j], valid k<8 (quad 0 only)
    float v[8];
#pragma unroll
    for (int j = 0; j < 8; ++j) v[j] = 0.f;
    if (quad == 0) {
      const float* rp = hw + col * 12;
      float4 g0 = *(const float4*)rp;
      float4 g1 = *(const float4*)(rp + 4);
      v[0] = g0.x; v[1] = g0.y; v[2] = g0.z; v[3] = g0.w;
      v[4] = g1.x; v[5] = g1.y; v[6] = g1.z; v[7] = g1.w;
    }
    bf16x8 PH, PL;
    split8(v, PH, PL);

    f32x4 e = {0.f, 0.f, 0.f, 0.f};
    e = mfma16(PH, BbH, e);
    e = mfma16(PH, BbL, e);
    e = mfma16(PL, BbH, e);

    float m0 = fmaxf(fmaxf(e[0], e[1]), fmaxf(e[2], e[3]));
    m0 = fmaxf(m0, __shfl_xor(m0, 16, 64));
    m0 = fmaxf(m0, __shfl_xor(m0, 32, 64));
    // m0: per-channel max (channel = col), replicated across quads.
    // final linear + log_sigmoid: sum over channels 0..7 within 16-group.
    float t = (col < 8) ? celuf(m0 + biasB) * wl : 0.f;
    t += __shfl_xor(t, 1, 64);
    t += __shfl_xor(t, 2, 64);
    t += __shfl_xor(t, 4, 64);
    t += __shfl_xor(t, 8, 64);
    if (lane == 0) out[p] = logsigf(t + bl);
  }
}

extern "C" void kernel_launch(void* const* d_in, const int* in_sizes, int n_in,
                              void* d_out, int out_size, void* d_ws, size_t ws_size,
                              hipStream_t stream) {
  const float* z_mask = (const float*)d_in[0];
  const float* pos4 = (const float*)d_in[1];
  const float* pos3 = (const float*)d_in[2];
  const float* pos2 = (const float*)d_in[3];
  const float* pos1 = (const float*)d_in[4];
  const float* w1a = (const float*)d_in[9];
  const float* b1a = (const float*)d_in[10];
  const float* w1b = (const float*)d_in[11];
  const float* b1b = (const float*)d_in[12];
  const float* w2a = (const float*)d_in[13];
  const float* b2a = (const float*)d_in[14];
  const float* w2b = (const float*)d_in[15];
  const float* b2b = (const float*)d_in[16];
  const float* w3a = (const float*)d_in[17];
  const float* b3a = (const float*)d_in[18];
  const float* w3b = (const float*)d_in[19];
  const float* b3b = (const float*)d_in[20];
  const float* wlin = (const float*)d_in[21];
  const float* blin = (const float*)d_in[22];
  const int* src3 = (const int*)d_in[23];
  const int* src2 = (const int*)d_in[25];
  const int* src1 = (const int*)d_in[27];

  float* x3 = (float*)d_ws;                 // [N3][32] = 8 MB
  float* x2 = x3 + (size_t)N3C * 32;        // [N2][16] = 8 MB (ws >= 16 MB)
  float* out = (float*)d_out;               // [N1] log-sigmoid logits

  l3_kernel<<<2048, 256, 0, stream>>>(z_mask, pos4, pos3, src3, w1a, b1a, w1b, b1b, x3);
  // 4096 blocks = 16384 waves -> 8 points/wave, 16 waves/SIMD occupancy target
  l2_kernel<<<4096, 256, 0, stream>>>(x3, pos3, pos2, src2, w2a, b2a, w2b, b2b, x2);
  // 8192 blocks = 32768 waves -> 8 points/wave
  l1_kernel<<<8192, 256, 0, stream>>>(x2, pos2, pos1, src1, w3a, b3a, w3b, b3b,
                                      wlin, blin, out);
}

// Round 3
// 373.911 us; speedup vs baseline: 2.9209x; 1.1677x over previous
//
#include <hip/hip_runtime.h>
#include <math.h>

#define N4C 32768
#define N3C 65536
#define N2C 131072
#define N1C 262144

typedef __bf16 bf16x8 __attribute__((ext_vector_type(8)));
typedef float f32x4 __attribute__((ext_vector_type(4)));

__device__ __forceinline__ f32x4 mfma16(bf16x8 a, bf16x8 b, f32x4 c) {
  return __builtin_amdgcn_mfma_f32_16x16x32_bf16(a, b, c, 0, 0, 0);
}

// fast celu: expm1(x) ~= __expf(x)-1. For |x| small, __expf(x)-1 has abs err
// ~1e-7 (fine vs 1.5e-2 threshold); __expf -> v_exp_f32 (few instrs, not libm).
__device__ __forceinline__ float celuf(float x) {
  return x > 0.f ? x : (__expf(x) - 1.f);
}

// log_sigmoid(x) = min(x,0) - log(1 + exp(-|x|)), fast intrinsics
__device__ __forceinline__ float logsigf(float x) {
  float e = __expf(-fabsf(x));
  return fminf(x, 0.f) - __logf(1.f + e);
}

// split f32 -> bf16 hi + bf16 lo (error feedback); hi+lo carries ~16 mantissa bits
__device__ __forceinline__ void split8(const float* v, bf16x8& hi, bf16x8& lo) {
#pragma unroll
  for (int j = 0; j < 8; ++j) {
    float f = v[j];
    __bf16 h = (__bf16)f;
    hi[j] = h;
    lo[j] = (__bf16)(f - (float)h);
  }
}

// ---------------------------------------------------------------------------
// Prep: z_mask [N4][64] f32 -> zsp [N4][128] bf16 rows = [hi 0..63][lo 0..63].
// Splits once at the producer so l3's A-fragments are raw 16-B loads.
// ---------------------------------------------------------------------------
__global__ __launch_bounds__(256) void zsplit_kernel(const float* __restrict__ z,
                                                     __bf16* __restrict__ zsp) {
  const int i = blockIdx.x * 256 + threadIdx.x;  // N4C*64 = 2M threads
  const float f = z[i];
  const __bf16 h = (__bf16)f;
  const int r = i >> 6, c = i & 63;
  zsp[r * 128 + c] = h;
  zsp[r * 128 + 64 + c] = (__bf16)(f - (float)h);
}

// ---------------------------------------------------------------------------
// Level 3: PointConv (64 -> 64 -> 32), MFMA bf16 hi/lo. Wave per point,
// 16 edges = M. A-frags load pre-split from zsp; output x3sp written pre-split
// (row = [hi 0..31][lo 0..31] bf16, 128 B) for l2's A-fragments.
// ---------------------------------------------------------------------------
__global__ __launch_bounds__(256) void l3_kernel(
    const __bf16* __restrict__ zsp, const float* __restrict__ pos4,
    const float* __restrict__ pos3, const int* __restrict__ src3,
    const float* __restrict__ w1a, const float* __restrict__ b1a,
    const float* __restrict__ w1b, const float* __restrict__ b1b,
    __bf16* __restrict__ x3sp) {
  __shared__ float hbuf[4][16 * 76];
  const int lane = threadIdx.x & 63;
  const int wid = threadIdx.x >> 6;
  const int col = lane & 15;
  const int quad = lane >> 4;
  float* hw = hbuf[wid];

  // B fragments layer a: B[k][n], k = c*32 + quad*8 + j, n = t*16 + col
  bf16x8 BaH[3][4], BaL[3][4];
#pragma unroll
  for (int c = 0; c < 3; ++c)
#pragma unroll
    for (int t = 0; t < 4; ++t) {
      float v[8];
#pragma unroll
      for (int j = 0; j < 8; ++j) {
        int k = c * 32 + quad * 8 + j;
        v[j] = (k < 67) ? w1a[k * 64 + t * 16 + col] : 0.f;
      }
      split8(v, BaH[c][t], BaL[c][t]);
    }
  bf16x8 BbH[2][2], BbL[2][2];
#pragma unroll
  for (int c = 0; c < 2; ++c)
#pragma unroll
    for (int t = 0; t < 2; ++t) {
      float v[8];
#pragma unroll
      for (int j = 0; j < 8; ++j) {
        int k = c * 32 + quad * 8 + j;
        v[j] = w1b[k * 32 + t * 16 + col];
      }
      split8(v, BbH[c][t], BbL[c][t]);
    }
  const float biasA0 = b1a[col], biasA1 = b1a[16 + col];
  const float biasA2 = b1a[32 + col], biasA3 = b1a[48 + col];
  const float biasB0 = b1b[col], biasB1 = b1b[16 + col];

  const int gwave = blockIdx.x * 4 + wid;
  const int nw = gridDim.x * 4;
  for (int p = gwave; p < N3C; p += nw) {
    const int s = src3[p * 16 + col];
    const float po0 = pos3[p * 3 + 0], po1 = pos3[p * 3 + 1], po2 = pos3[p * 3 + 2];

    const __bf16* zr = zsp + (size_t)s * 128;
    bf16x8 AH[3], AL[3];
    AH[0] = *(const bf16x8*)(zr + quad * 8);
    AH[1] = *(const bf16x8*)(zr + 32 + quad * 8);
    AL[0] = *(const bf16x8*)(zr + 64 + quad * 8);
    AL[1] = *(const bf16x8*)(zr + 96 + quad * 8);
#pragma unroll
    for (int j = 0; j < 8; ++j) { AH[2][j] = (__bf16)0.f; AL[2][j] = (__bf16)0.f; }
    if (quad == 0) {
      float r0 = pos4[s * 3 + 0] - po0;
      float r1 = pos4[s * 3 + 1] - po1;
      float r2 = pos4[s * 3 + 2] - po2;
      __bf16 h0 = (__bf16)r0, h1 = (__bf16)r1, h2 = (__bf16)r2;
      AH[2][0] = h0; AH[2][1] = h1; AH[2][2] = h2;
      AL[2][0] = (__bf16)(r0 - (float)h0);
      AL[2][1] = (__bf16)(r1 - (float)h1);
      AL[2][2] = (__bf16)(r2 - (float)h2);
    }

    f32x4 d[4];
#pragma unroll
    for (int t = 0; t < 4; ++t) {
      f32x4 acc = {0.f, 0.f, 0.f, 0.f};
#pragma unroll
      for (int c = 0; c < 3; ++c) {
        acc = mfma16(AH[c], BaH[c][t], acc);
        acc = mfma16(AH[c], BaL[c][t], acc);
        acc = mfma16(AL[c], BaH[c][t], acc);
      }
      d[t] = acc;
    }
#pragma unroll
    for (int r = 0; r < 4; ++r) {
      float* bp = hw + (quad * 4 + r) * 76 + col;
      bp[0]  = celuf(d[0][r] + biasA0);
      bp[16] = celuf(d[1][r] + biasA1);
      bp[32] = celuf(d[2][r] + biasA2);
      bp[48] = celuf(d[3][r] + biasA3);
    }
    // same-wave LDS, no barrier needed
    bf16x8 PH[2], PL[2];
#pragma unroll
    for (int c = 0; c < 2; ++c) {
      const float* rp = hw + col * 76 + c * 32 + quad * 8;
      float v[8];
      float4 g0 = *(const float4*)rp;
      float4 g1 = *(const float4*)(rp + 4);
      v[0] = g0.x; v[1] = g0.y; v[2] = g0.z; v[3] = g0.w;
      v[4] = g1.x; v[5] = g1.y; v[6] = g1.z; v[7] = g1.w;
      split8(v, PH[c], PL[c]);
    }
    f32x4 e[2];
#pragma unroll
    for (int t = 0; t < 2; ++t) {
      f32x4 acc = {0.f, 0.f, 0.f, 0.f};
#pragma unroll
      for (int c = 0; c < 2; ++c) {
        acc = mfma16(PH[c], BbH[c][t], acc);
        acc = mfma16(PH[c], BbL[c][t], acc);
        acc = mfma16(PL[c], BbH[c][t], acc);
      }
      e[t] = acc;
    }
    float m0 = fmaxf(fmaxf(e[0][0], e[0][1]), fmaxf(e[0][2], e[0][3]));
    float m1 = fmaxf(fmaxf(e[1][0], e[1][1]), fmaxf(e[1][2], e[1][3]));
    m0 = fmaxf(m0, __shfl_xor(m0, 16, 64));
    m0 = fmaxf(m0, __shfl_xor(m0, 32, 64));
    m1 = fmaxf(m1, __shfl_xor(m1, 16, 64));
    m1 = fmaxf(m1, __shfl_xor(m1, 32, 64));
    if (lane < 16) {
      float f0 = celuf(m0 + biasB0);
      float f1 = celuf(m1 + biasB1);
      __bf16 h0 = (__bf16)f0, h1 = (__bf16)f1;
      __bf16* row = x3sp + (size_t)p * 64;
      row[col] = h0;
      row[16 + col] = h1;
      row[32 + col] = (__bf16)(f0 - (float)h0);
      row[48 + col] = (__bf16)(f1 - (float)h1);
    }
  }
}

// ---------------------------------------------------------------------------
// Level 2: PointConv (32 -> 16 -> 16), MFMA wave-per-point. A-frags load
// pre-split from x3sp; output x2 = plain bf16 (4 MB -> L2-resident for l1).
// ---------------------------------------------------------------------------
__global__ __launch_bounds__(256) void l2_kernel(
    const __bf16* __restrict__ x3sp, const float* __restrict__ pos3,
    const float* __restrict__ pos2, const int* __restrict__ src2,
    const float* __restrict__ w2a, const float* __restrict__ b2a,
    const float* __restrict__ w2b, const float* __restrict__ b2b,
    __bf16* __restrict__ x2) {
  __shared__ float hbuf[4][16 * 20];
  const int lane = threadIdx.x & 63;
  const int wid = threadIdx.x >> 6;
  const int col = lane & 15;
  const int quad = lane >> 4;
  float* hw = hbuf[wid];

  bf16x8 BaH[2], BaL[2];
#pragma unroll
  for (int c = 0; c < 2; ++c) {
    float v[8];
#pragma unroll
    for (int j = 0; j < 8; ++j) {
      int k = c * 32 + quad * 8 + j;
      v[j] = (k < 35) ? w2a[k * 16 + col] : 0.f;
    }
    split8(v, BaH[c], BaL[c]);
  }
  bf16x8 BbH, BbL;
  {
    float v[8];
#pragma unroll
    for (int j = 0; j < 8; ++j) {
      int k = quad * 8 + j;
      v[j] = (k < 16) ? w2b[k * 16 + col] : 0.f;
    }
    split8(v, BbH, BbL);
  }
  const float biasA = b2a[col];
  const float biasB = b2b[col];

  const int gwave = blockIdx.x * 4 + wid;
  const int nw = gridDim.x * 4;
  for (int p = gwave; p < N2C; p += nw) {
    const int s = src2[p * 16 + col];
    const float po0 = pos2[p * 3 + 0], po1 = pos2[p * 3 + 1], po2 = pos2[p * 3 + 2];

    const __bf16* xr = x3sp + (size_t)s * 64;
    bf16x8 AH0 = *(const bf16x8*)(xr + quad * 8);
    bf16x8 AL0 = *(const bf16x8*)(xr + 32 + quad * 8);
    bf16x8 AH1, AL1;
#pragma unroll
    for (int j = 0; j < 8; ++j) { AH1[j] = (__bf16)0.f; AL1[j] = (__bf16)0.f; }
    if (quad == 0) {
      float r0 = pos3[s * 3 + 0] - po0;
      float r1 = pos3[s * 3 + 1] - po1;
      float r2 = pos3[s * 3 + 2] - po2;
      __bf16 h0 = (__bf16)r0, h1 = (__bf16)r1, h2 = (__bf16)r2;
      AH1[0] = h0; AH1[1] = h1; AH1[2] = h2;
      AL1[0] = (__bf16)(r0 - (float)h0);
      AL1[1] = (__bf16)(r1 - (float)h1);
      AL1[2] = (__bf16)(r2 - (float)h2);
    }

    f32x4 d = {0.f, 0.f, 0.f, 0.f};
    d = mfma16(AH0, BaH[0], d);
    d = mfma16(AH0, BaL[0], d);
    d = mfma16(AL0, BaH[0], d);
    d = mfma16(AH1, BaH[1], d);
    d = mfma16(AH1, BaL[1], d);
    d = mfma16(AL1, BaH[1], d);
#pragma unroll
    for (int r = 0; r < 4; ++r)
      hw[(quad * 4 + r) * 20 + col] = celuf(d[r] + biasA);

    float v[8];
#pragma unroll
    for (int j = 0; j < 8; ++j) v[j] = 0.f;
    if (quad < 2) {
      const float* rp = hw + col * 20 + quad * 8;
      float4 g0 = *(const float4*)rp;
      float4 g1 = *(const float4*)(rp + 4);
      v[0] = g0.x; v[1] = g0.y; v[2] = g0.z; v[3] = g0.w;
      v[4] = g1.x; v[5] = g1.y; v[6] = g1.z; v[7] = g1.w;
    }
    bf16x8 PH, PL;
    split8(v, PH, PL);

    f32x4 e = {0.f, 0.f, 0.f, 0.f};
    e = mfma16(PH, BbH, e);
    e = mfma16(PH, BbL, e);
    e = mfma16(PL, BbH, e);

    float m0 = fmaxf(fmaxf(e[0], e[1]), fmaxf(e[2], e[3]));
    m0 = fmaxf(m0, __shfl_xor(m0, 16, 64));
    m0 = fmaxf(m0, __shfl_xor(m0, 32, 64));
    if (lane < 16) x2[(size_t)p * 16 + col] = (__bf16)celuf(m0 + biasB);
  }
}

// ---------------------------------------------------------------------------
// Level 1: scalar-per-edge fp32 (64 lanes = 64 edges = 4 points per wave).
// Tiny MLP (19->8->8): full-precision VALU beats MFMA overhead here.
// x2 is bf16 [N2][16] = 4 MB -> L2-resident gathers.
// ---------------------------------------------------------------------------
__global__ __launch_bounds__(256, 4) void l1_kernel(
    const __bf16* __restrict__ x2, const float* __restrict__ pos2,
    const float* __restrict__ pos1, const int* __restrict__ src1,
    const float* __restrict__ w3a, const float* __restrict__ b3a,
    const float* __restrict__ w3b, const float* __restrict__ b3b,
    const float* __restrict__ wlin, const float* __restrict__ blin,
    float* __restrict__ out) {
  const int lane = threadIdx.x & 63;
  const int wid = threadIdx.x >> 6;
  const int e = lane & 15;   // edge within point
  const int g = lane >> 4;   // point within wave (4 points/wave)
  const int gwave = blockIdx.x * 4 + wid;
  const int nw = gridDim.x * 4;

  for (int pb = gwave * 4; pb < N1C; pb += nw * 4) {
    const int p = pb + g;
    const int s = src1[p * 16 + e];

    float feat[16];
    {
      const uint4 u0 = *(const uint4*)(x2 + (size_t)s * 16);
      const uint4 u1 = *(const uint4*)(x2 + (size_t)s * 16 + 8);
      const unsigned uu[8] = {u0.x, u0.y, u0.z, u0.w, u1.x, u1.y, u1.z, u1.w};
#pragma unroll
      for (int j = 0; j < 8; ++j) {
        feat[2 * j]     = __uint_as_float(uu[j] << 16);
        feat[2 * j + 1] = __uint_as_float(uu[j] & 0xffff0000u);
      }
    }
    const float r0 = pos2[s * 3 + 0] - pos1[p * 3 + 0];
    const float r1 = pos2[s * 3 + 1] - pos1[p * 3 + 1];
    const float r2 = pos2[s * 3 + 2] - pos1[p * 3 + 2];

    float m[8];
#pragma unroll
    for (int c = 0; c < 8; ++c) m[c] = b3b[c];
#pragma unroll
    for (int l = 0; l < 8; ++l) {
      float h = b3a[l];
#pragma unroll
      for (int k = 0; k < 16; ++k) h = fmaf(feat[k], w3a[k * 8 + l], h);
      h = fmaf(r0, w3a[128 + l], h);
      h = fmaf(r1, w3a[136 + l], h);
      h = fmaf(r2, w3a[144 + l], h);
      h = celuf(h);
#pragma unroll
      for (int c = 0; c < 8; ++c) m[c] = fmaf(h, w3b[l * 8 + c], m[c]);
    }
    // segment max over the 16 edge-lanes of this point
#pragma unroll
    for (int c = 0; c < 8; ++c) {
      float v = m[c];
      v = fmaxf(v, __shfl_xor(v, 1, 64));
      v = fmaxf(v, __shfl_xor(v, 2, 64));
      v = fmaxf(v, __shfl_xor(v, 4, 64));
      v = fmaxf(v, __shfl_xor(v, 8, 64));
      m[c] = v;
    }
    float logit = blin[0];
#pragma unroll
    for (int c = 0; c < 8; ++c) logit = fmaf(celuf(m[c]), wlin[c], logit);
    if (e == 0) out[p] = logsigf(logit);
  }
}

extern "C" void kernel_launch(void* const* d_in, const int* in_sizes, int n_in,
                              void* d_out, int out_size, void* d_ws, size_t ws_size,
                              hipStream_t stream) {
  const float* z_mask = (const float*)d_in[0];
  const float* pos4 = (const float*)d_in[1];
  const float* pos3 = (const float*)d_in[2];
  const float* pos2 = (const float*)d_in[3];
  const float* pos1 = (const float*)d_in[4];
  const float* w1a = (const float*)d_in[9];
  const float* b1a = (const float*)d_in[10];
  const float* w1b = (const float*)d_in[11];
  const float* b1b = (const float*)d_in[12];
  const float* w2a = (const float*)d_in[13];
  const float* b2a = (const float*)d_in[14];
  const float* w2b = (const float*)d_in[15];
  const float* b2b = (const float*)d_in[16];
  const float* w3a = (const float*)d_in[17];
  const float* b3a = (const float*)d_in[18];
  const float* w3b = (const float*)d_in[19];
  const float* b3b = (const float*)d_in[20];
  const float* wlin = (const float*)d_in[21];
  const float* blin = (const float*)d_in[22];
  const int* src3 = (const int*)d_in[23];
  const int* src2 = (const int*)d_in[25];
  const int* src1 = (const int*)d_in[27];

  // ws layout (16 MB): [x3sp 8 MB][regionB 8 MB]
  // regionB holds zsp (live: prep..l3) then x2 (live: l2..l1) — disjoint lifetimes.
  __bf16* x3sp = (__bf16*)d_ws;                       // [N3][64] bf16 hi/lo
  __bf16* zsp = (__bf16*)((char*)d_ws + (size_t)N3C * 64 * 2);  // [N4][128] bf16
  __bf16* x2 = zsp;                                   // [N2][16] bf16 (4 MB)
  float* out = (float*)d_out;

  zsplit_kernel<<<(N4C * 64) / 256, 256, 0, stream>>>(z_mask, zsp);
  l3_kernel<<<2048, 256, 0, stream>>>(zsp, pos4, pos3, src3, w1a, b1a, w1b, b1b, x3sp);
  l2_kernel<<<4096, 256, 0, stream>>>(x3sp, pos3, pos2, src2, w2a, b2a, w2b, b2b, x2);
  l1_kernel<<<4096, 256, 0, stream>>>(x2, pos2, pos1, src1, w3a, b3a, w3b, b3b,
                                      wlin, blin, out);
}

// Round 4
// 321.978 us; speedup vs baseline: 3.3920x; 1.1613x over previous
//
#include <hip/hip_runtime.h>
#include <math.h>

#define N4C 32768
#define N3C 65536
#define N2C 131072
#define N1C 262144

typedef _Float16 f16x8 __attribute__((ext_vector_type(8)));
typedef _Float16 f16x4 __attribute__((ext_vector_type(4)));
typedef float f32x4 __attribute__((ext_vector_type(4)));

__device__ __forceinline__ f32x4 mfma16(f16x8 a, f16x8 b, f32x4 c) {
  return __builtin_amdgcn_mfma_f32_16x16x32_f16(a, b, c, 0, 0, 0);
}

// fast celu: expm1(x) ~= __expf(x)-1 (v_exp_f32, abs err ~1e-7)
__device__ __forceinline__ float celuf(float x) {
  return x > 0.f ? x : (__expf(x) - 1.f);
}

// log_sigmoid(x) = min(x,0) - log(1 + exp(-|x|))
__device__ __forceinline__ float logsigf(float x) {
  float e = __expf(-fabsf(x));
  return fminf(x, 0.f) - __logf(1.f + e);
}

// ---------------------------------------------------------------------------
// Prep: z_mask [N4*64] f32 -> zf f16 (4 MB table -> L2-resident for l3 gathers)
// ---------------------------------------------------------------------------
__global__ __launch_bounds__(256) void zhalf_kernel(const float* __restrict__ z,
                                                    _Float16* __restrict__ zf) {
  const int i = (blockIdx.x * 256 + threadIdx.x) * 4;
  float4 f = *(const float4*)(z + i);
  f16x4 h;
  h[0] = (_Float16)f.x; h[1] = (_Float16)f.y;
  h[2] = (_Float16)f.z; h[3] = (_Float16)f.w;
  *(f16x4*)(zf + i) = h;
}

// ---------------------------------------------------------------------------
// Level 3: PointConv (64 -> 64 -> 32), f16 MFMA, wave per point (16 edges = M).
// Single-plane f16 activations AND weights: 16 MFMA/point (was 48), gather
// row = 128 B (was 256 B hi/lo bf16). zf table 4 MB -> L2-cacheable.
// ---------------------------------------------------------------------------
__global__ __launch_bounds__(256) void l3_kernel(
    const _Float16* __restrict__ zf, const float* __restrict__ pos4,
    const float* __restrict__ pos3, const int* __restrict__ src3,
    const float* __restrict__ w1a, const float* __restrict__ b1a,
    const float* __restrict__ w1b, const float* __restrict__ b1b,
    _Float16* __restrict__ x3f) {
  __shared__ float hbuf[4][16 * 76];
  const int lane = threadIdx.x & 63;
  const int wid = threadIdx.x >> 6;
  const int col = lane & 15;   // MFMA n / A row m
  const int quad = lane >> 4;  // k-subchunk selector
  float* hw = hbuf[wid];

  // B frags layer a: B[k][n], k = c*32 + quad*8 + j (K=67 pad 96), n = t*16+col
  f16x8 Ba[3][4];
#pragma unroll
  for (int c = 0; c < 3; ++c)
#pragma unroll
    for (int t = 0; t < 4; ++t)
#pragma unroll
      for (int j = 0; j < 8; ++j) {
        int k = c * 32 + quad * 8 + j;
        Ba[c][t][j] = (k < 67) ? (_Float16)w1a[k * 64 + t * 16 + col] : (_Float16)0.f;
      }
  f16x8 Bb[2][2];
#pragma unroll
  for (int c = 0; c < 2; ++c)
#pragma unroll
    for (int t = 0; t < 2; ++t)
#pragma unroll
      for (int j = 0; j < 8; ++j) {
        int k = c * 32 + quad * 8 + j;
        Bb[c][t][j] = (_Float16)w1b[k * 32 + t * 16 + col];
      }
  const float biasA0 = b1a[col], biasA1 = b1a[16 + col];
  const float biasA2 = b1a[32 + col], biasA3 = b1a[48 + col];
  const float biasB0 = b1b[col], biasB1 = b1b[16 + col];

  const int gwave = blockIdx.x * 4 + wid;
  const int nw = gridDim.x * 4;
  for (int p = gwave; p < N3C; p += nw) {
    const int s = src3[p * 16 + col];  // edge m = col
    const float po0 = pos3[p * 3 + 0], po1 = pos3[p * 3 + 1], po2 = pos3[p * 3 + 2];

    const _Float16* zr = zf + (size_t)s * 64;
    f16x8 A0 = *(const f16x8*)(zr + quad * 8);        // k 0..31
    f16x8 A1 = *(const f16x8*)(zr + 32 + quad * 8);   // k 32..63
    f16x8 A2;
#pragma unroll
    for (int j = 0; j < 8; ++j) A2[j] = (_Float16)0.f;
    if (quad == 0) {                                   // k 64..66 = rel
      A2[0] = (_Float16)(pos4[s * 3 + 0] - po0);
      A2[1] = (_Float16)(pos4[s * 3 + 1] - po1);
      A2[2] = (_Float16)(pos4[s * 3 + 2] - po2);
    }

    f32x4 d[4];
#pragma unroll
    for (int t = 0; t < 4; ++t) {
      f32x4 acc = {0.f, 0.f, 0.f, 0.f};
      acc = mfma16(A0, Ba[0][t], acc);
      acc = mfma16(A1, Ba[1][t], acc);
      acc = mfma16(A2, Ba[2][t], acc);
      d[t] = acc;
    }
    // C layout: row = quad*4 + r, col = n. celu -> LDS [16][76].
#pragma unroll
    for (int r = 0; r < 4; ++r) {
      float* bp = hw + (quad * 4 + r) * 76 + col;
      bp[0]  = celuf(d[0][r] + biasA0);
      bp[16] = celuf(d[1][r] + biasA1);
      bp[32] = celuf(d[2][r] + biasA2);
      bp[48] = celuf(d[3][r] + biasA3);
    }
    // same-wave LDS, in-order: no barrier. A'[m=col][k=c*32+quad*8+j]
    f16x8 P[2];
#pragma unroll
    for (int c = 0; c < 2; ++c) {
      const float* rp = hw + col * 76 + c * 32 + quad * 8;
      float4 g0 = *(const float4*)rp;
      float4 g1 = *(const float4*)(rp + 4);
      P[c][0] = (_Float16)g0.x; P[c][1] = (_Float16)g0.y;
      P[c][2] = (_Float16)g0.z; P[c][3] = (_Float16)g0.w;
      P[c][4] = (_Float16)g1.x; P[c][5] = (_Float16)g1.y;
      P[c][6] = (_Float16)g1.z; P[c][7] = (_Float16)g1.w;
    }
    f32x4 e[2];
#pragma unroll
    for (int t = 0; t < 2; ++t) {
      f32x4 acc = {0.f, 0.f, 0.f, 0.f};
      acc = mfma16(P[0], Bb[0][t], acc);
      acc = mfma16(P[1], Bb[1][t], acc);
      e[t] = acc;
    }
    float m0 = fmaxf(fmaxf(e[0][0], e[0][1]), fmaxf(e[0][2], e[0][3]));
    float m1 = fmaxf(fmaxf(e[1][0], e[1][1]), fmaxf(e[1][2], e[1][3]));
    m0 = fmaxf(m0, __shfl_xor(m0, 16, 64));
    m0 = fmaxf(m0, __shfl_xor(m0, 32, 64));
    m1 = fmaxf(m1, __shfl_xor(m1, 16, 64));
    m1 = fmaxf(m1, __shfl_xor(m1, 32, 64));
    if (lane < 16) {
      _Float16* row = x3f + (size_t)p * 32;
      row[col]      = (_Float16)celuf(m0 + biasB0);  // max(x)+b == max(x+b)
      row[16 + col] = (_Float16)celuf(m1 + biasB1);
    }
  }
}

// ---------------------------------------------------------------------------
// Level 2: PointConv (32 -> 16 -> 16), f16 MFMA wave-per-point. 3 MFMA/point.
// x3f table 4 MB -> L2-resident gathers (64 B/row).
// ---------------------------------------------------------------------------
__global__ __launch_bounds__(256) void l2_kernel(
    const _Float16* __restrict__ x3f, const float* __restrict__ pos3,
    const float* __restrict__ pos2, const int* __restrict__ src2,
    const float* __restrict__ w2a, const float* __restrict__ b2a,
    const float* __restrict__ w2b, const float* __restrict__ b2b,
    _Float16* __restrict__ x2f) {
  __shared__ float hbuf[4][16 * 20];
  const int lane = threadIdx.x & 63;
  const int wid = threadIdx.x >> 6;
  const int col = lane & 15;
  const int quad = lane >> 4;
  float* hw = hbuf[wid];

  f16x8 Ba0, Ba1, Bb;
#pragma unroll
  for (int j = 0; j < 8; ++j) {
    int k = quad * 8 + j;
    Ba0[j] = (_Float16)w2a[k * 16 + col];                       // k 0..31
    Ba1[j] = (k + 32 < 35) ? (_Float16)w2a[(k + 32) * 16 + col] // k 32..34
                           : (_Float16)0.f;
    Bb[j] = (k < 16) ? (_Float16)w2b[k * 16 + col] : (_Float16)0.f;
  }
  const float biasA = b2a[col];
  const float biasB = b2b[col];

  const int gwave = blockIdx.x * 4 + wid;
  const int nw = gridDim.x * 4;
  for (int p = gwave; p < N2C; p += nw) {
    const int s = src2[p * 16 + col];
    const float po0 = pos2[p * 3 + 0], po1 = pos2[p * 3 + 1], po2 = pos2[p * 3 + 2];

    const _Float16* xr = x3f + (size_t)s * 32;
    f16x8 A0 = *(const f16x8*)(xr + quad * 8);  // k 0..31 = feat
    f16x8 A1;
#pragma unroll
    for (int j = 0; j < 8; ++j) A1[j] = (_Float16)0.f;
    if (quad == 0) {                             // k 32..34 = rel
      A1[0] = (_Float16)(pos3[s * 3 + 0] - po0);
      A1[1] = (_Float16)(pos3[s * 3 + 1] - po1);
      A1[2] = (_Float16)(pos3[s * 3 + 2] - po2);
    }

    f32x4 d = {0.f, 0.f, 0.f, 0.f};
    d = mfma16(A0, Ba0, d);
    d = mfma16(A1, Ba1, d);
#pragma unroll
    for (int r = 0; r < 4; ++r)
      hw[(quad * 4 + r) * 20 + col] = celuf(d[r] + biasA);

    f16x8 P;
#pragma unroll
    for (int j = 0; j < 8; ++j) P[j] = (_Float16)0.f;
    if (quad < 2) {  // k 0..15 valid
      const float* rp = hw + col * 20 + quad * 8;
      float4 g0 = *(const float4*)rp;
      float4 g1 = *(const float4*)(rp + 4);
      P[0] = (_Float16)g0.x; P[1] = (_Float16)g0.y;
      P[2] = (_Float16)g0.z; P[3] = (_Float16)g0.w;
      P[4] = (_Float16)g1.x; P[5] = (_Float16)g1.y;
      P[6] = (_Float16)g1.z; P[7] = (_Float16)g1.w;
    }
    f32x4 e = {0.f, 0.f, 0.f, 0.f};
    e = mfma16(P, Bb, e);

    float m0 = fmaxf(fmaxf(e[0], e[1]), fmaxf(e[2], e[3]));
    m0 = fmaxf(m0, __shfl_xor(m0, 16, 64));
    m0 = fmaxf(m0, __shfl_xor(m0, 32, 64));
    if (lane < 16) x2f[(size_t)p * 16 + col] = (_Float16)celuf(m0 + biasB);
  }
}

// ---------------------------------------------------------------------------
// Level 1: PointConv (16 -> 8 -> 8) + final linear + log_sigmoid, f16 MFMA.
// 2 MFMA/point; weights in VGPR fragments (no SGPR-pressure s_load storm that
// sank the scalar version). x2f table 4 MB -> L2-resident (32 B/row gathers).
// ---------------------------------------------------------------------------
__global__ __launch_bounds__(256) void l1_kernel(
    const _Float16* __restrict__ x2f, const float* __restrict__ pos2,
    const float* __restrict__ pos1, const int* __restrict__ src1,
    const float* __restrict__ w3a, const float* __restrict__ b3a,
    const float* __restrict__ w3b, const float* __restrict__ b3b,
    const float* __restrict__ wlin, const float* __restrict__ blin,
    float* __restrict__ out) {
  __shared__ float hbuf[4][16 * 12];
  const int lane = threadIdx.x & 63;
  const int wid = threadIdx.x >> 6;
  const int col = lane & 15;
  const int quad = lane >> 4;
  float* hw = hbuf[wid];

  f16x8 Ba, Bb;
#pragma unroll
  for (int j = 0; j < 8; ++j) {
    int k = quad * 8 + j;
    Ba[j] = (k < 19 && col < 8) ? (_Float16)w3a[k * 8 + col] : (_Float16)0.f;
    Bb[j] = (k < 8 && col < 8) ? (_Float16)w3b[k * 8 + col] : (_Float16)0.f;
  }
  const float biasA = (col < 8) ? b3a[col] : 0.f;
  const float biasB = (col < 8) ? b3b[col] : 0.f;
  const float wl = (col < 8) ? wlin[col] : 0.f;
  const float bl = blin[0];

  const int gwave = blockIdx.x * 4 + wid;
  const int nw = gridDim.x * 4;
  for (int p = gwave; p < N1C; p += nw) {
    const int s = src1[p * 16 + col];

    // A[m=col=edge][k=quad*8+j]: quads 0,1 = feat 0..15; quad 2: rel k=16..18
    f16x8 A;
#pragma unroll
    for (int j = 0; j < 8; ++j) A[j] = (_Float16)0.f;
    if (quad < 2) {
      A = *(const f16x8*)(x2f + (size_t)s * 16 + quad * 8);
    } else if (quad == 2) {
      A[0] = (_Float16)(pos2[s * 3 + 0] - pos1[p * 3 + 0]);
      A[1] = (_Float16)(pos2[s * 3 + 1] - pos1[p * 3 + 1]);
      A[2] = (_Float16)(pos2[s * 3 + 2] - pos1[p * 3 + 2]);
    }

    f32x4 d = {0.f, 0.f, 0.f, 0.f};
    d = mfma16(A, Ba, d);

    if (col < 8) {
#pragma unroll
      for (int r = 0; r < 4; ++r)
        hw[(quad * 4 + r) * 12 + col] = celuf(d[r] + biasA);
    }
    f16x8 P;
#pragma unroll
    for (int j = 0; j < 8; ++j) P[j] = (_Float16)0.f;
    if (quad == 0) {  // k = 0..7 valid
      const float* rp = hw + col * 12;
      float4 g0 = *(const float4*)rp;
      float4 g1 = *(const float4*)(rp + 4);
      P[0] = (_Float16)g0.x; P[1] = (_Float16)g0.y;
      P[2] = (_Float16)g0.z; P[3] = (_Float16)g0.w;
      P[4] = (_Float16)g1.x; P[5] = (_Float16)g1.y;
      P[6] = (_Float16)g1.z; P[7] = (_Float16)g1.w;
    }
    f32x4 e = {0.f, 0.f, 0.f, 0.f};
    e = mfma16(P, Bb, e);

    float m0 = fmaxf(fmaxf(e[0], e[1]), fmaxf(e[2], e[3]));
    m0 = fmaxf(m0, __shfl_xor(m0, 16, 64));
    m0 = fmaxf(m0, __shfl_xor(m0, 32, 64));
    // final linear + log_sigmoid: sum celu(max)+bias over channels 0..7
    float t = (col < 8) ? celuf(m0 + biasB) * wl : 0.f;
    t += __shfl_xor(t, 1, 64);
    t += __shfl_xor(t, 2, 64);
    t += __shfl_xor(t, 4, 64);
    t += __shfl_xor(t, 8, 64);
    if (lane == 0) out[p] = logsigf(t + bl);
  }
}

extern "C" void kernel_launch(void* const* d_in, const int* in_sizes, int n_in,
                              void* d_out, int out_size, void* d_ws, size_t ws_size,
                              hipStream_t stream) {
  const float* z_mask = (const float*)d_in[0];
  const float* pos4 = (const float*)d_in[1];
  const float* pos3 = (const float*)d_in[2];
  const float* pos2 = (const float*)d_in[3];
  const float* pos1 = (const float*)d_in[4];
  const float* w1a = (const float*)d_in[9];
  const float* b1a = (const float*)d_in[10];
  const float* w1b = (const float*)d_in[11];
  const float* b1b = (const float*)d_in[12];
  const float* w2a = (const float*)d_in[13];
  const float* b2a = (const float*)d_in[14];
  const float* w2b = (const float*)d_in[15];
  const float* b2b = (const float*)d_in[16];
  const float* w3a = (const float*)d_in[17];
  const float* b3a = (const float*)d_in[18];
  const float* w3b = (const float*)d_in[19];
  const float* b3b = (const float*)d_in[20];
  const float* wlin = (const float*)d_in[21];
  const float* blin = (const float*)d_in[22];
  const int* src3 = (const int*)d_in[23];
  const int* src2 = (const int*)d_in[25];
  const int* src1 = (const int*)d_in[27];

  // ws layout: [x3f 4 MB][regionB 4 MB]
  // regionB: zf (live prep..l3) then x2f (live l2..l1) — disjoint lifetimes.
  _Float16* x3f = (_Float16*)d_ws;                              // [N3][32] f16
  _Float16* zf = (_Float16*)((char*)d_ws + (size_t)N3C * 32 * 2);  // [N4][64] f16
  _Float16* x2f = zf;                                           // [N2][16] f16
  float* out = (float*)d_out;

  zhalf_kernel<<<(N4C * 64) / (256 * 4), 256, 0, stream>>>(z_mask, zf);
  l3_kernel<<<2048, 256, 0, stream>>>(zf, pos4, pos3, src3, w1a, b1a, w1b, b1b, x3f);
  l2_kernel<<<8192, 256, 0, stream>>>(x3f, pos3, pos2, src2, w2a, b2a, w2b, b2b, x2f);
  l1_kernel<<<8192, 256, 0, stream>>>(x2f, pos2, pos1, src1, w3a, b3a, w3b, b3b,
                                      wlin, blin, out);
}